// Round 21
// baseline (60.768 us; speedup 1.0000x reference)
//
#include <hip/hip_runtime.h>

// 5-layer MLP [B,64]->32->12->8->6->2, fp32 in/out.
// Layer 0 on matrix cores, TRANSPOSED (D' = W0^T x x^T) via
// v_mfma_f32_32x32x16_bf16, 3-pass truncated-bf16 split; feature halves
// aligned with v_permlane32_swap_b32, bias+ReLU IN-PLACE in the
// accumulators (no xr[] materialization). Register-direct staging (no LDS,
// R19-proven path) but in a RING OF 4 8-VGPR chunk slots (2xfloat4 = one
// MFMA k-slice): phase p consumes slot p&3, issues chunk p+3 into slot
// (p+3)&3 (consumed at p-1 -> WAR-safe; 3-phase latency cover; compiler
// emits counted vmcnt(6)). Total ~120 VGPR -> __launch_bounds__(256,4)
// gives 4 blocks/CU = 16 waves/CU (2x R19's TLP). NT=4, grid=1024 ->
// single dispatch round. Tail layers scalar fmaf (s_load weights).

typedef __attribute__((ext_vector_type(8))) short short8;
typedef __attribute__((ext_vector_type(16))) float f32x16;
typedef __attribute__((ext_vector_type(4))) unsigned uint4v;

#define BLOCK 256   // 4 independent waves/block
#define NT 4        // 64-row tiles per wave

__device__ __forceinline__ unsigned fbits(float x) {
    return __builtin_bit_cast(unsigned, x);
}
__device__ __forceinline__ float asf(unsigned u) {
    return __builtin_bit_cast(float, u);
}
// (hi16(ub)<<16) | hi16(ua)  -- one v_perm_b32
__device__ __forceinline__ unsigned packhi(unsigned ua, unsigned ub) {
    return __builtin_amdgcn_perm(ub, ua, 0x07060302u);
}
// 8 floats -> 8 truncated bf16 (element j = k-index j)
__device__ __forceinline__ short8 mk_hi(const float* f) {
    uint4v w;
#pragma unroll
    for (int t = 0; t < 4; ++t)
        w[t] = packhi(fbits(f[2 * t]), fbits(f[2 * t + 1]));
    return __builtin_bit_cast(short8, w);
}
// 8 floats -> bf16 of the truncation residuals
__device__ __forceinline__ short8 mk_lo(const float* f) {
    uint4v w;
#pragma unroll
    for (int t = 0; t < 4; ++t) {
        const float la = f[2 * t]     - asf(fbits(f[2 * t])     & 0xFFFF0000u);
        const float lb = f[2 * t + 1] - asf(fbits(f[2 * t + 1]) & 0xFFFF0000u);
        w[t] = packhi(fbits(la), fbits(lb));
    }
    return __builtin_bit_cast(short8, w);
}
#define MFMA(A, B, C) __builtin_amdgcn_mfma_f32_32x32x16_bf16(A, B, C, 0, 0, 0)

template <int IN, int OUT, bool RELU>
__device__ __forceinline__ void layer(const float* __restrict__ W,
                                      const float* __restrict__ b,
                                      const float* h_in, float* h_out) {
#pragma unroll
    for (int o = 0; o < OUT; ++o) h_out[o] = b[o];
#pragma unroll
    for (int i = 0; i < IN; ++i) {
        const float v = h_in[i];
#pragma unroll
        for (int o = 0; o < OUT; ++o)
            h_out[o] = fmaf(v, W[i * OUT + o], h_out[o]);   // uniform -> s_load
    }
    if (RELU) {
#pragma unroll
        for (int o = 0; o < OUT; ++o) h_out[o] = fmaxf(h_out[o], 0.0f);
    }
}

__global__ __launch_bounds__(BLOCK, 4) void mlp_kernel(
        const float* __restrict__ x,
        const float* __restrict__ W0, const float* __restrict__ b0,
        const float* __restrict__ W1, const float* __restrict__ b1,
        const float* __restrict__ W2, const float* __restrict__ b2,
        const float* __restrict__ W3, const float* __restrict__ b3,
        const float* __restrict__ W4, const float* __restrict__ b4,
        float* __restrict__ out, int nrows) {
    const int t = threadIdx.x;
    const int wv = t >> 6;
    const int lane = t & 63;

    const long long row0 = ((long long)blockIdx.x * 4 + wv) * (NT * 64);
    // Per-lane base: row lane&31, k-half (lane>>5)*32 bytes.
    const char* hbase = reinterpret_cast<const char*>(x + row0 * 64) +
                        (lane & 31) * 256 + (lane >> 5) * 32;

    const int hA = lane >> 5;
    const int colB = lane & 31;

    // --- W0^T fragments (A operand), built once, held in registers.
    //     k-step s: A[o = lane&31][k = 16s + 8*hA + j] = W0[k][o].
    short8 W0h_, W0l_, W1h_, W1l_, W2h_, W2l_, W3h_, W3l_;
    {
        float wf[8];
#define LOADW(s, BH, BL)                                                \
        {                                                               \
            _Pragma("unroll")                                           \
            for (int j = 0; j < 8; ++j)                                 \
                wf[j] = W0[((s) * 16 + 8 * hA + j) * 32 + colB];        \
            BH = mk_hi(wf);                                             \
            BL = mk_lo(wf);                                             \
        }
        LOADW(0, W0h_, W0l_)
        LOADW(1, W1h_, W1l_)
        LOADW(2, W2h_, W2l_)
        LOADW(3, W3h_, W3l_)
#undef LOADW
    }

    // Ring of 4 chunk slots, 2 float4 each (one MFMA k-slice per slot).
    float4 S0a, S0b, S1a, S1b, S2a, S2b, S3a, S3b;

// Issue chunk CIDX (within-tile 0..7: half=CIDX>>2, s=CIDX&3) of the tile
// at byte offset TB into a slot.
#define ISS(CIDX, TB, Sa, Sb)                                              \
    Sa = *reinterpret_cast<const float4*>(                                 \
        hbase + (TB) + ((CIDX) >> 2) * 8192 + ((CIDX) & 3) * 64);          \
    Sb = *reinterpret_cast<const float4*>(                                 \
        hbase + (TB) + ((CIDX) >> 2) * 8192 + ((CIDX) & 3) * 64 + 16);

#define SB __builtin_amdgcn_sched_barrier(0);

// One K=16 step from a slot (3-pass bf16 split).
#define KST(Sa, Sb, WH, WL, ACC)                                           \
    {                                                                      \
        float f[8];                                                        \
        f[0] = Sa.x; f[1] = Sa.y; f[2] = Sa.z; f[3] = Sa.w;                \
        f[4] = Sb.x; f[5] = Sb.y; f[6] = Sb.z; f[7] = Sb.w;                \
        const short8 Xh = mk_hi(f), Xl = mk_lo(f);                         \
        ACC = MFMA(WH, Xh, ACC);                                           \
        ACC = MFMA(WL, Xh, ACC);                                           \
        ACC = MFMA(WH, Xl, ACC);                                           \
    }

    // Prologue: chunks 0..2 of tile 0 into slots 0..2.
    ISS(0, 0, S0a, S0b)
    ISS(1, 0, S1a, S1b)
    ISS(2, 0, S2a, S2b)
    SB

#pragma unroll 1
    for (int tt = 0; tt < NT; ++tt) {
        const long long toff = (long long)tt * 16384;
        const long long noff = toff + 16384;

        f32x16 accA, accB;   // D'[o][col]: accA cols = rows 0-31, accB 32-63
#pragma unroll
        for (int r = 0; r < 16; ++r) { accA[r] = 0.0f; accB[r] = 0.0f; }

        // p0: issue c3->S3; consume S0 (accA, s0)
        ISS(3, toff, S3a, S3b) SB KST(S0a, S0b, W0h_, W0l_, accA)
        // p1: issue c4->S0; consume S1 (accA, s1)
        ISS(4, toff, S0a, S0b) SB KST(S1a, S1b, W1h_, W1l_, accA)
        // p2: issue c5->S1; consume S2 (accA, s2)
        ISS(5, toff, S1a, S1b) SB KST(S2a, S2b, W2h_, W2l_, accA)
        // p3: issue c6->S2; consume S3 (accA, s3)
        ISS(6, toff, S2a, S2b) SB KST(S3a, S3b, W3h_, W3l_, accA)
        // p4: issue c7->S3; consume S0 (accB, s0)
        ISS(7, toff, S3a, S3b) SB KST(S0a, S0b, W0h_, W0l_, accB)
        // p5: issue next-tile c0->S0; consume S1 (accB, s1)
        if (tt + 1 < NT) { ISS(0, noff, S0a, S0b) }
        SB KST(S1a, S1b, W1h_, W1l_, accB)
        // p6: issue next-tile c1->S1; consume S2 (accB, s2)
        if (tt + 1 < NT) { ISS(1, noff, S1a, S1b) }
        SB KST(S2a, S2b, W2h_, W2l_, accB)
        // p7: issue next-tile c2->S2; consume S3 (accB, s3)
        if (tt + 1 < NT) { ISS(2, noff, S2a, S2b) }
        SB KST(S3a, S3b, W3h_, W3l_, accB)

        // --- Epilogue IN-PLACE: permlane-swap feature halves, bias+ReLU.
        //     After this accA[reg] = h0[f0], accB[reg] = h0[f0+4],
        //     f0 = (reg&3)+8*(reg>>2), h0 = this lane's row.
#pragma unroll
        for (int reg = 0; reg < 16; ++reg) {
            float a = accA[reg];
            float b = accB[reg];
            asm("v_permlane32_swap_b32 %0, %1" : "+v"(a), "+v"(b));
            const int f0 = (reg & 3) + 8 * (reg >> 2);
            accA[reg] = fmaxf(a + b0[f0],     0.0f);
            accB[reg] = fmaxf(b + b0[f0 + 4], 0.0f);
        }

// h0[f] accessor: compile-time mapping into the accumulators.
#define H0(f) ((((f) >> 2) & 1) ? accB[((f) & 3) + 4 * ((f) >> 3)]          \
                                : accA[((f) & 3) + 4 * ((f) >> 3)])

        // Layer 1 (32->12) reading h0 straight from the accumulators.
        float h1[12];
#pragma unroll
        for (int o = 0; o < 12; ++o) h1[o] = b1[o];
#pragma unroll
        for (int i = 0; i < 32; ++i) {
            const float v = H0(i);
#pragma unroll
            for (int o = 0; o < 12; ++o)
                h1[o] = fmaf(v, W1[i * 12 + o], h1[o]);
        }
#pragma unroll
        for (int o = 0; o < 12; ++o) h1[o] = fmaxf(h1[o], 0.0f);
#undef H0

        // Remaining tail (next tile's chunks 0-2 in flight during these).
        float h2[8], h3[6], h4[2];
        layer<12, 8, true>(W2, b2, h1, h2);
        layer<8, 6, true>(W3, b3, h2, h3);
        layer<6, 2, false>(W4, b4, h3, h4);

        reinterpret_cast<float2*>(out)[row0 + tt * 64 + lane] =
            make_float2(h4[0], h4[1]);
    }
#undef ISS
#undef KST
#undef SB
}

extern "C" void kernel_launch(void* const* d_in, const int* in_sizes, int n_in,
                              void* d_out, int out_size, void* d_ws, size_t ws_size,
                              hipStream_t stream) {
    const float* x  = (const float*)d_in[0];
    const float* W0 = (const float*)d_in[1];
    const float* b0 = (const float*)d_in[2];
    const float* W1 = (const float*)d_in[3];
    const float* b1 = (const float*)d_in[4];
    const float* W2 = (const float*)d_in[5];
    const float* b2 = (const float*)d_in[6];
    const float* W3 = (const float*)d_in[7];
    const float* b3 = (const float*)d_in[8];
    const float* W4 = (const float*)d_in[9];
    const float* b4 = (const float*)d_in[10];
    float* out = (float*)d_out;

    const int nrows = in_sizes[0] / 64;                 // 1,048,576
    const int rows_per_block = 4 * NT * 64;             // 1024
    const int grid = nrows / rows_per_block;            // 1024 (exact)

    mlp_kernel<<<grid, BLOCK, 0, stream>>>(x, W0, b0, W1, b1, W2, b2,
                                           W3, b3, W4, b4, out, nrows);
}

// Round 22
// 55.695 us; speedup vs baseline: 1.0911x; 1.0911x over previous
//
#include <hip/hip_runtime.h>

// 5-layer MLP [B,64]->32->12->8->6->2, fp32 in/out.
// Layer 0 on matrix cores, TRANSPOSED (D' = W0^T x x^T) via
// v_mfma_f32_32x32x16_bf16, 3-pass truncated-bf16 split; permlane32_swap
// epilogue (R15-proven). R22: DENSE HBM sourcing on the vector path --
// global_load_dwordx4 with lane-consecutive addresses (1KB/instr, the m13 /
// fillBuffer pattern) into 2 named register banks, then ds_write_b128 into
// a wave-private padded LDS tile (row stride 272B), fragment ds_read_b128
// out. Prefetch distance 2 half-tiles; compiler-derived counted waits; no
// __syncthreads (LDS wave-private). Tail layers scalar fmaf (s_load).

typedef __attribute__((ext_vector_type(8))) short short8;
typedef __attribute__((ext_vector_type(16))) float f32x16;
typedef __attribute__((ext_vector_type(4))) unsigned uint4v;

#define BLOCK 128   // 2 waves/block
#define NT 8        // 64-row tiles per wave; 2 half-tile phases per tile
#define RSTRIDE 272 // 256 + 16 pad: breaks the 256B bank-degeneracy
#define HBYTES 8704 // 32 rows * 272

__device__ __forceinline__ unsigned fbits(float x) {
    return __builtin_bit_cast(unsigned, x);
}
__device__ __forceinline__ float asf(unsigned u) {
    return __builtin_bit_cast(float, u);
}
__device__ __forceinline__ unsigned packhi(unsigned ua, unsigned ub) {
    return __builtin_amdgcn_perm(ub, ua, 0x07060302u);
}
__device__ __forceinline__ short8 mk_hi(const float* f) {
    uint4v w;
#pragma unroll
    for (int t = 0; t < 4; ++t)
        w[t] = packhi(fbits(f[2 * t]), fbits(f[2 * t + 1]));
    return __builtin_bit_cast(short8, w);
}
__device__ __forceinline__ short8 mk_lo(const float* f) {
    uint4v w;
#pragma unroll
    for (int t = 0; t < 4; ++t) {
        const float la = f[2 * t]     - asf(fbits(f[2 * t])     & 0xFFFF0000u);
        const float lb = f[2 * t + 1] - asf(fbits(f[2 * t + 1]) & 0xFFFF0000u);
        w[t] = packhi(fbits(la), fbits(lb));
    }
    return __builtin_bit_cast(short8, w);
}
#define MFMA(A, B, C) __builtin_amdgcn_mfma_f32_32x32x16_bf16(A, B, C, 0, 0, 0)

template <int IN, int OUT, bool RELU>
__device__ __forceinline__ void layer(const float* __restrict__ W,
                                      const float* __restrict__ b,
                                      const float* h_in, float* h_out) {
#pragma unroll
    for (int o = 0; o < OUT; ++o) h_out[o] = b[o];
#pragma unroll
    for (int i = 0; i < IN; ++i) {
        const float v = h_in[i];
#pragma unroll
        for (int o = 0; o < OUT; ++o)
            h_out[o] = fmaf(v, W[i * OUT + o], h_out[o]);   // uniform -> s_load
    }
    if (RELU) {
#pragma unroll
        for (int o = 0; o < OUT; ++o) h_out[o] = fmaxf(h_out[o], 0.0f);
    }
}

__global__ __launch_bounds__(BLOCK, 2) void mlp_kernel(
        const float* __restrict__ x,
        const float* __restrict__ W0, const float* __restrict__ b0,
        const float* __restrict__ W1, const float* __restrict__ b1,
        const float* __restrict__ W2, const float* __restrict__ b2,
        const float* __restrict__ W3, const float* __restrict__ b3,
        const float* __restrict__ W4, const float* __restrict__ b4,
        float* __restrict__ out, int nrows) {
    extern __shared__ char lds[];
    const int t = threadIdx.x;
    const int wv = t >> 6;
    const int lane = t & 63;
    char* const buf0 = lds + wv * (2 * HBYTES);
    char* const buf1 = buf0 + HBYTES;

    const long long row0 = ((long long)blockIdx.x * 2 + wv) * (NT * 64);
    const char* xbase = reinterpret_cast<const char*>(x + row0 * 64);

    const int hA = lane >> 5;
    const int colB = lane & 31;

    // Dense-load lane offset; LDS write base (row i*4+(lane>>4), col lane&15).
    const int wbase = (lane >> 4) * RSTRIDE + (lane & 15) * 16;
    // Fragment read base: own row = lane&31, k-half hA.
    const int rb = (lane & 31) * RSTRIDE + hA * 32;

    // --- W0^T fragments (A operand), built once, held in registers.
    short8 W0h_, W0l_, W1h_, W1l_, W2h_, W2l_, W3h_, W3l_;
    {
        float wf[8];
#define LOADW(s, BH, BL)                                                \
        {                                                               \
            _Pragma("unroll")                                           \
            for (int j = 0; j < 8; ++j)                                 \
                wf[j] = W0[((s) * 16 + 8 * hA + j) * 32 + colB];        \
            BH = mk_hi(wf);                                             \
            BL = mk_lo(wf);                                             \
        }
        LOADW(0, W0h_, W0l_)
        LOADW(1, W1h_, W1l_)
        LOADW(2, W2h_, W2l_)
        LOADW(3, W3h_, W3l_)
#undef LOADW
    }

    // Two 8-float4 register banks.
    float4 P0_0, P0_1, P0_2, P0_3, P0_4, P0_5, P0_6, P0_7;
    float4 P1_0, P1_1, P1_2, P1_3, P1_4, P1_5, P1_6, P1_7;

#define SB __builtin_amdgcn_sched_barrier(0);

// Dense load of half-tile h (8KB contiguous): lane-consecutive float4.
#define LOADD(h, P)                                                        \
    {                                                                      \
        const char* s0 = xbase + (long long)(h) * 8192 + lane * 16;        \
        P##_0 = *reinterpret_cast<const float4*>(s0 + 0 * 1024);           \
        P##_1 = *reinterpret_cast<const float4*>(s0 + 1 * 1024);           \
        P##_2 = *reinterpret_cast<const float4*>(s0 + 2 * 1024);           \
        P##_3 = *reinterpret_cast<const float4*>(s0 + 3 * 1024);           \
        P##_4 = *reinterpret_cast<const float4*>(s0 + 4 * 1024);           \
        P##_5 = *reinterpret_cast<const float4*>(s0 + 5 * 1024);           \
        P##_6 = *reinterpret_cast<const float4*>(s0 + 6 * 1024);           \
        P##_7 = *reinterpret_cast<const float4*>(s0 + 7 * 1024);           \
    }                                                                      \
    SB

// Scatter bank P into LDS row-major (row stride 272B). Load i of lane L is
// global bytes i*1024 + L*16 -> row i*4 + (L>>4), col (L&15)*16.
#define WLDS(P, BUF)                                                       \
    *reinterpret_cast<float4*>((BUF) + wbase + 0 * 1088) = P##_0;          \
    *reinterpret_cast<float4*>((BUF) + wbase + 1 * 1088) = P##_1;          \
    *reinterpret_cast<float4*>((BUF) + wbase + 2 * 1088) = P##_2;          \
    *reinterpret_cast<float4*>((BUF) + wbase + 3 * 1088) = P##_3;          \
    *reinterpret_cast<float4*>((BUF) + wbase + 4 * 1088) = P##_4;          \
    *reinterpret_cast<float4*>((BUF) + wbase + 5 * 1088) = P##_5;          \
    *reinterpret_cast<float4*>((BUF) + wbase + 6 * 1088) = P##_6;          \
    *reinterpret_cast<float4*>((BUF) + wbase + 7 * 1088) = P##_7;          \
    SB

// One K=16 step s from LDS buffer (3-pass bf16 split).
#define KST(BUF, s, WH, WL, ACC)                                           \
    {                                                                      \
        float f[8];                                                        \
        const float4 q0 =                                                  \
            *reinterpret_cast<const float4*>((BUF) + rb + (s) * 64);       \
        const float4 q1 =                                                  \
            *reinterpret_cast<const float4*>((BUF) + rb + (s) * 64 + 16);  \
        f[0] = q0.x; f[1] = q0.y; f[2] = q0.z; f[3] = q0.w;                \
        f[4] = q1.x; f[5] = q1.y; f[6] = q1.z; f[7] = q1.w;                \
        const short8 Xh = mk_hi(f), Xl = mk_lo(f);                         \
        ACC = MFMA(WH, Xh, ACC);                                           \
        ACC = MFMA(WL, Xh, ACC);                                           \
        ACC = MFMA(WH, Xl, ACC);                                           \
    }

    // Prologue: halves 0,1 into banks; half 0 into buf0.
    LOADD(0, P0)
    LOADD(1, P1)
    WLDS(P0, buf0)

#pragma unroll 1
    for (int tt = 0; tt < NT; ++tt) {
        f32x16 accA, accB;
#pragma unroll
        for (int r = 0; r < 16; ++r) { accA[r] = 0.0f; accB[r] = 0.0f; }

        // Phase A (half h=2tt in buf0): prefetch half h+2 into P0;
        // stage half h+1 (P1) into buf1; consume buf0.
        if (2 * tt + 2 < 2 * NT) { LOADD(2 * tt + 2, P0) }
        WLDS(P1, buf1)
        KST(buf0, 0, W0h_, W0l_, accA)
        KST(buf0, 1, W1h_, W1l_, accA)
        KST(buf0, 2, W2h_, W2l_, accA)
        KST(buf0, 3, W3h_, W3l_, accA)

        // Phase B (half h+1 in buf1): prefetch half h+3 into P1;
        // stage half h+2 (P0) into buf0; consume buf1.
        if (2 * tt + 3 < 2 * NT) { LOADD(2 * tt + 3, P1) }
        if (2 * tt + 2 < 2 * NT) { WLDS(P0, buf0) }
        KST(buf1, 0, W0h_, W0l_, accB)
        KST(buf1, 1, W1h_, W1l_, accB)
        KST(buf1, 2, W2h_, W2l_, accB)
        KST(buf1, 3, W3h_, W3l_, accB)

        // --- permlane epilogue: align feature halves, bias+ReLU in-reg.
        float xr[32];
#pragma unroll
        for (int reg = 0; reg < 16; ++reg) {
            float a = accA[reg];
            float b = accB[reg];
            asm("v_permlane32_swap_b32 %0, %1" : "+v"(a), "+v"(b));
            const int f0 = (reg & 3) + 8 * (reg >> 2);
            xr[f0]     = fmaxf(a + b0[f0],     0.0f);
            xr[f0 + 4] = fmaxf(b + b0[f0 + 4], 0.0f);
        }

        // Tail layers (next tile's loads/stage in flight during these).
        float h1[12], h2[8], h3[6], h4[2];
        layer<32, 12, true>(W1, b1, xr, h1);
        layer<12, 8, true>(W2, b2, h1, h2);
        layer<8, 6, true>(W3, b3, h2, h3);
        layer<6, 2, false>(W4, b4, h3, h4);

        reinterpret_cast<float2*>(out)[row0 + tt * 64 + lane] =
            make_float2(h4[0], h4[1]);
    }
#undef LOADD
#undef WLDS
#undef KST
#undef SB
}

extern "C" void kernel_launch(void* const* d_in, const int* in_sizes, int n_in,
                              void* d_out, int out_size, void* d_ws, size_t ws_size,
                              hipStream_t stream) {
    const float* x  = (const float*)d_in[0];
    const float* W0 = (const float*)d_in[1];
    const float* b0 = (const float*)d_in[2];
    const float* W1 = (const float*)d_in[3];
    const float* b1 = (const float*)d_in[4];
    const float* W2 = (const float*)d_in[5];
    const float* b2 = (const float*)d_in[6];
    const float* W3 = (const float*)d_in[7];
    const float* b3 = (const float*)d_in[8];
    const float* W4 = (const float*)d_in[9];
    const float* b4 = (const float*)d_in[10];
    float* out = (float*)d_out;

    const int nrows = in_sizes[0] / 64;                 // 1,048,576
    const int rows_per_block = 2 * NT * 64;             // 1024
    const int grid = nrows / rows_per_block;            // 1024 (exact)
    const size_t shmem = 2 * 2 * HBYTES;                // 34,816 B/block

    mlp_kernel<<<grid, BLOCK, shmem, stream>>>(x, W0, b0, W1, b1, W2, b2,
                                               W3, b3, W4, b4, out, nrows);
}